// Round 5
// baseline (154.798 us; speedup 1.0000x reference)
//
#include <hip/hip_runtime.h>
#include <hip/hip_bf16.h>
#include <cstdint>
#include <cstddef>

// Problem constants
#define NB_B 8
#define NL   64
#define NT   512
#define CF   128
#define HD   128
#define NK   10
#define NE   1024

// d_out flat offsets (fp32 elements), reference return order:
// pi[P,10], sigma[P,10], mu[P,10], dist[P,1], atom_types[512,28], bond_types[1024,6], C_batch[P]
static constexpr size_t P_TOT    = (size_t)NB_B * NL * NT;     // 262144
static constexpr size_t PI_OFF   = 0;
static constexpr size_t SIG_OFF  = P_TOT * 10;
static constexpr size_t MU_OFF   = SIG_OFF + P_TOT * 10;
static constexpr size_t DIST_OFF = MU_OFF + P_TOT * 10;
static constexpr size_t AT_OFF   = DIST_OFF + P_TOT;
static constexpr size_t BD_OFF   = AT_OFF + 512 * 28;
static constexpr size_t CB_OFF   = BD_OFF + NE * 6;

typedef __attribute__((ext_vector_type(8))) short short8;
typedef __attribute__((ext_vector_type(4))) float floatx4;
typedef __attribute__((ext_vector_type(2))) float floatx2;

union U8 { short8 s8; unsigned int u[4]; };

__device__ __forceinline__ unsigned short f2bf(float f) {
    unsigned int x = __float_as_uint(f);
    x = (x + 0x7FFFu + ((x >> 16) & 1u)) >> 16;   // RNE
    return (unsigned short)x;
}
// HW packed f32x2 -> bf16x2 (v_cvt_pk_bf16_f32 on gfx950); a lands in low 16.
__device__ __forceinline__ unsigned int pk2bf(float a, float b) {
    __hip_bfloat162 h = __float22bfloat162_rn(make_float2(a, b));
    return *reinterpret_cast<unsigned int*>(&h);
}

// ---------------------------------------------------------------------------
// ONE fused kernel. Blocks [0,512): one per (b,l) — full pipeline with
// per-block redundant zt-GEMM (no workspace, no inter-kernel dependency).
// Blocks [512,568): atom_types. Blocks [568,592): bond_types.
//
// Main-block pipeline (4 chunks of 128 t):
//  pre:    W1-bottom -> LDS bf16 transposed W1t[n][k]; zl_raw row (fp32 VALU);
//          c0[h]=zl_raw+b1-rmean, s[h]=gamma*rsqrt(rvar+eps), bt[h]=beta;
//          head-weight B-frags (bf16) resident in VGPRs.
//  stage0: zt-chunk GEMM [128t x 128c] @ [128c x 128h] via MFMA (wave-local
//          M rows); epilogue fuses BN+ELU: C = ELU((acc+c0)*s+bt) -> Ztile LDS.
//  stageA: heads GEMM [128t x 128h] @ [128h x 32n] via MFMA -> Dl (aliases
//          Ztile after barrier).
//  stageB: softmax(pi) / ELU(sig)+1.1 / ELU(mu)+1.0 / dist / C_batch.
// MFMA frag conventions validated R3/R4: A[m=lane&15][k=quad*8+j],
// B[k][n=lane&15], D col=lane&15, row=quad*4+r.
// ---------------------------------------------------------------------------
__global__ __launch_bounds__(256) void k_fused(
    const float* __restrict__ hl,
    const float* __restrict__ ht,
    const int*   __restrict__ eidx,
    const float* __restrict__ W1,
    const float* __restrict__ b1,
    const float* __restrict__ gamma_,
    const float* __restrict__ beta_,
    const float* __restrict__ rmean,
    const float* __restrict__ rvar,
    const float* __restrict__ Wpi,
    const float* __restrict__ bpi,
    const float* __restrict__ Wsig,
    const float* __restrict__ bsig,
    const float* __restrict__ Wmu,
    const float* __restrict__ bmu,
    const float* __restrict__ Wat,
    const float* __restrict__ bat,
    const float* __restrict__ Wbd,
    const float* __restrict__ bbd,
    const float* __restrict__ hlpos,
    const float* __restrict__ htpos,
    float* __restrict__ out)
{
    __shared__ unsigned short W1t[128 * 136];                  // 34816 B
    __shared__ __align__(16) unsigned char ldsu[128 * 136 * 2]; // Ztile(bf16) | Dl(f32) alias
    __shared__ float zpart[256];
    __shared__ float c0s[128], svs[128], bts[128];
    __shared__ float biass[32];
    __shared__ float pls[3];

    const int blk = blockIdx.x;
    const int tid = threadIdx.x;

    if (blk >= 512) {
        if (blk < 568) {
            // atom_types: 512x28 (56 blocks * 256 = 14336)
            const int oi = (blk - 512) * 256 + tid;
            const int r = oi / 28, n = oi - r * 28;
            float acc = bat[n];
            #pragma unroll 4
            for (int c = 0; c < CF; ++c)
                acc += hl[(size_t)r * CF + c] * Wat[c * 28 + n];
            out[AT_OFF + oi] = acc;
        } else {
            // bond_types: 1024x6 (24 blocks * 256 = 6144)
            const int oi = (blk - 568) * 256 + tid;
            const int e = oi / 6, n = oi - e * 6;
            const int s0 = eidx[e], s1 = eidx[NE + e];
            float acc = bbd[n];
            #pragma unroll 4
            for (int c = 0; c < CF; ++c) {
                acc += hl[(size_t)s0 * CF + c] * Wbd[c * 6 + n];
                acc += hl[(size_t)s1 * CF + c] * Wbd[(CF + c) * 6 + n];
            }
            out[BD_OFF + oi] = acc;
        }
        return;
    }

    unsigned short* Zt = (unsigned short*)ldsu;   // [128][136] bf16
    float*          Dl = (float*)ldsu;            // [128][33]  f32 (after barrier)

    const int b    = blk >> 6;
    const int l    = blk & 63;
    const int lane = tid & 63;
    const int wave = tid >> 6;
    const int m    = lane & 15;
    const int quad = lane >> 4;

    if (tid < 32) {
        float v = 0.f;
        if (tid < 10)      v = bpi[tid];
        else if (tid < 20) v = bsig[tid - 10];
        else if (tid < 30) v = bmu[tid - 20];
        biass[tid] = v;
    } else if (tid < 35) {
        pls[tid - 32] = hlpos[(size_t)(b * NL + l) * 3 + (tid - 32)];
    }

    // ---- W1 bottom half -> LDS bf16 transposed: W1t[n][k] = W1[CF+k][n] ----
    {
        const int kb0 = tid >> 5;            // 0..7
        const int n0  = (tid & 31) * 4;      // 0..124
        #pragma unroll 4
        for (int p = 0; p < 16; ++p) {
            const int k = kb0 + p * 8;
            const float4 v = *(const float4*)&W1[(size_t)(CF + k) * HD + n0];
            const unsigned int u01 = pk2bf(v.x, v.y);
            const unsigned int u23 = pk2bf(v.z, v.w);
            W1t[(n0 + 0) * 136 + k] = (unsigned short)(u01 & 0xffffu);
            W1t[(n0 + 1) * 136 + k] = (unsigned short)(u01 >> 16);
            W1t[(n0 + 2) * 136 + k] = (unsigned short)(u23 & 0xffffu);
            W1t[(n0 + 3) * 136 + k] = (unsigned short)(u23 >> 16);
        }
    }

    // ---- zl_raw partial dot products (fp32): zpart[tid] ----
    {
        const int h = tid & 127, half = tid >> 7;
        const float* hr = hl + (size_t)(b * NL + l) * CF + half * 64;
        const float* wc = W1 + (size_t)(half * 64) * HD + h;
        float s = 0.f;
        #pragma unroll 8
        for (int c = 0; c < 64; ++c) s += hr[c] * wc[(size_t)c * HD];
        zpart[tid] = s;
    }

    // ---- head-weight B fragments (resident, bf16) ----
    short8 bfragH[2][4];
    #pragma unroll
    for (int nt = 0; nt < 2; ++nt) {
        const int n = nt * 16 + m;
        const float* hw = (n < 10) ? (Wpi + n) : (n < 20) ? (Wsig + n - 10)
                        : (n < 30) ? (Wmu + n - 20) : Wpi;
        #pragma unroll
        for (int kb = 0; kb < 4; ++kb) {
            #pragma unroll
            for (int j = 0; j < 8; ++j) {
                const int k = kb * 32 + quad * 8 + j;
                const float v = (n < 30) ? hw[(size_t)k * NK] : 0.f;
                bfragH[nt][kb][j] = (short)f2bf(v);
            }
        }
    }
    __syncthreads();

    if (tid < 128) {
        const int h = tid;
        c0s[h] = zpart[h] + zpart[h + 128] + b1[h] - rmean[h];
        svs[h] = gamma_[h] * rsqrtf(rvar[h] + 1e-4f);
        bts[h] = beta_[h];
    }
    __syncthreads();

    for (int ch = 0; ch < 4; ++ch) {
        // ---- stage 0: zt-chunk GEMM + fused BN/ELU -> Ztile (wave-local rows) ----
        floatx4 acc0[2][8];
        #pragma unroll
        for (int i = 0; i < 2; ++i)
            #pragma unroll
            for (int j = 0; j < 8; ++j)
                acc0[i][j] = (floatx4){0.f, 0.f, 0.f, 0.f};

        const float* htbase = ht + (size_t)(b * NT + ch * 128) * CF;
        #pragma unroll
        for (int kb = 0; kb < 4; ++kb) {
            const int k0 = kb * 32 + quad * 8;
            short8 a[2];
            #pragma unroll
            for (int mt = 0; mt < 2; ++mt) {
                const int row = wave * 32 + mt * 16 + m;
                const float* ap = htbase + (size_t)row * CF + k0;
                const float4 f0 = *(const float4*)ap;
                const float4 f1 = *(const float4*)(ap + 4);
                U8 t;
                t.u[0] = pk2bf(f0.x, f0.y);
                t.u[1] = pk2bf(f0.z, f0.w);
                t.u[2] = pk2bf(f1.x, f1.y);
                t.u[3] = pk2bf(f1.z, f1.w);
                a[mt] = t.s8;
            }
            #pragma unroll
            for (int nt = 0; nt < 8; ++nt) {
                const short8 bf = *(const short8*)&W1t[(nt * 16 + m) * 136 + k0];
                acc0[0][nt] = __builtin_amdgcn_mfma_f32_16x16x32_bf16(a[0], bf, acc0[0][nt], 0, 0, 0);
                acc0[1][nt] = __builtin_amdgcn_mfma_f32_16x16x32_bf16(a[1], bf, acc0[1][nt], 0, 0, 0);
            }
        }
        #pragma unroll
        for (int nt = 0; nt < 8; ++nt) {
            const int col = nt * 16 + m;
            const float c0v = c0s[col], sv = svs[col], btv = bts[col];
            #pragma unroll
            for (int mt = 0; mt < 2; ++mt) {
                const int rbase = wave * 32 + mt * 16 + quad * 4;
                float e[4];
                #pragma unroll
                for (int r = 0; r < 4; ++r) {
                    const float z = (acc0[mt][nt][r] + c0v) * sv + btv;
                    e[r] = (z > 0.f) ? z : (__expf(z) - 1.f);
                }
                const unsigned int u01 = pk2bf(e[0], e[1]);
                const unsigned int u23 = pk2bf(e[2], e[3]);
                Zt[(rbase + 0) * 136 + col] = (unsigned short)(u01 & 0xffffu);
                Zt[(rbase + 1) * 136 + col] = (unsigned short)(u01 >> 16);
                Zt[(rbase + 2) * 136 + col] = (unsigned short)(u23 & 0xffffu);
                Zt[(rbase + 3) * 136 + col] = (unsigned short)(u23 >> 16);
            }
        }

        // ---- stage A: heads MFMA (reads wave-local Ztile rows) ----
        floatx4 acc2[2][2];
        #pragma unroll
        for (int i = 0; i < 2; ++i)
            #pragma unroll
            for (int j = 0; j < 2; ++j)
                acc2[i][j] = (floatx4){0.f, 0.f, 0.f, 0.f};

        #pragma unroll
        for (int kb = 0; kb < 4; ++kb) {
            const int ko = kb * 32 + quad * 8;
            const short8 a0 = *(const short8*)&Zt[(wave * 32 + m) * 136 + ko];
            const short8 a1 = *(const short8*)&Zt[(wave * 32 + 16 + m) * 136 + ko];
            #pragma unroll
            for (int nt = 0; nt < 2; ++nt) {
                acc2[0][nt] = __builtin_amdgcn_mfma_f32_16x16x32_bf16(a0, bfragH[nt][kb], acc2[0][nt], 0, 0, 0);
                acc2[1][nt] = __builtin_amdgcn_mfma_f32_16x16x32_bf16(a1, bfragH[nt][kb], acc2[1][nt], 0, 0, 0);
            }
        }
        __syncthreads();   // all Ztile reads done (Dl aliases Ztile)

        #pragma unroll
        for (int mt = 0; mt < 2; ++mt)
            #pragma unroll
            for (int nt = 0; nt < 2; ++nt)
                #pragma unroll
                for (int r = 0; r < 4; ++r) {
                    const int row = wave * 32 + mt * 16 + quad * 4 + r;
                    const int col = nt * 16 + m;
                    Dl[row * 33 + col] = acc2[mt][nt][r];
                }
        __syncthreads();

        // ---- stage B: epilogues (fp32 stores) ----
        const size_t gp = ((size_t)(b * NL + l)) * NT + ch * 128 + (tid & 127);
        if (tid < 128) {
            const int p = tid;
            float v[10];
            float mx = -1e30f;
            #pragma unroll
            for (int n = 0; n < 10; ++n) {
                v[n] = Dl[p * 33 + n] + biass[n];
                mx = fmaxf(mx, v[n]);
            }
            float s = 0.f;
            #pragma unroll
            for (int n = 0; n < 10; ++n) { v[n] = __expf(v[n] - mx); s += v[n]; }
            const float inv = 1.f / s;
            floatx2* po = (floatx2*)(out + PI_OFF + gp * 10);
            #pragma unroll
            for (int n = 0; n < 5; ++n) po[n] = (floatx2){v[2*n] * inv, v[2*n+1] * inv};
        } else {
            const int p = tid - 128;
            float sg[10], mv[10];
            #pragma unroll
            for (int n = 0; n < 10; ++n) {
                const float x = Dl[p * 33 + 10 + n] + biass[10 + n];
                sg[n] = ((x > 0.f) ? x : (__expf(x) - 1.f)) + 1.1f;
                const float y = Dl[p * 33 + 20 + n] + biass[20 + n];
                mv[n] = ((y > 0.f) ? y : (__expf(y) - 1.f)) + 1.0f;
            }
            floatx2* ps = (floatx2*)(out + SIG_OFF + gp * 10);
            floatx2* pm = (floatx2*)(out + MU_OFF  + gp * 10);
            #pragma unroll
            for (int n = 0; n < 5; ++n) {
                ps[n] = (floatx2){sg[2*n], sg[2*n+1]};
                pm[n] = (floatx2){mv[2*n], mv[2*n+1]};
            }
            const int t = ch * 128 + p;
            const size_t pb = (size_t)(b * NT + t) * 3;
            const float dx = pls[0] - htpos[pb + 0];
            const float dy = pls[1] - htpos[pb + 1];
            const float dz = pls[2] - htpos[pb + 2];
            out[DIST_OFF + gp] = sqrtf(dx * dx + dy * dy + dz * dz);
            out[CB_OFF + gp]   = (float)b;
        }
        __syncthreads();   // Dl reads done before next chunk's Ztile writes
    }
}

// ---------------------------------------------------------------------------
extern "C" void kernel_launch(void* const* d_in, const int* in_sizes, int n_in,
                              void* d_out, int out_size, void* d_ws, size_t ws_size,
                              hipStream_t stream)
{
    const float* hl     = (const float*)d_in[0];
    const float* ht     = (const float*)d_in[1];
    const float* hlpos  = (const float*)d_in[2];
    const float* htpos  = (const float*)d_in[3];
    const int*   eidx   = (const int*)d_in[4];
    const float* W1     = (const float*)d_in[5];
    const float* b1     = (const float*)d_in[6];
    const float* gamma_ = (const float*)d_in[7];
    const float* beta_  = (const float*)d_in[8];
    const float* rmean  = (const float*)d_in[9];
    const float* rvar   = (const float*)d_in[10];
    const float* Wpi    = (const float*)d_in[11];
    const float* bpi    = (const float*)d_in[12];
    const float* Wsig   = (const float*)d_in[13];
    const float* bsig   = (const float*)d_in[14];
    const float* Wmu    = (const float*)d_in[15];
    const float* bmu    = (const float*)d_in[16];
    const float* Wat    = (const float*)d_in[17];
    const float* bat    = (const float*)d_in[18];
    const float* Wbd    = (const float*)d_in[19];
    const float* bbd    = (const float*)d_in[20];

    float* out = (float*)d_out;

    k_fused<<<592, 256, 0, stream>>>(hl, ht, eidx, W1, b1, gamma_, beta_, rmean, rvar,
                                     Wpi, bpi, Wsig, bsig, Wmu, bmu,
                                     Wat, bat, Wbd, bbd, hlpos, htpos, out);
}

// Round 6
// 140.366 us; speedup vs baseline: 1.1028x; 1.1028x over previous
//
#include <hip/hip_runtime.h>
#include <hip/hip_bf16.h>
#include <cstdint>
#include <cstddef>

// Problem constants
#define NB_B 8
#define NL   64
#define NT   512
#define CF   128
#define HD   128
#define NK   10
#define NE   1024

// d_out flat offsets (fp32 elements), reference return order:
// pi[P,10], sigma[P,10], mu[P,10], dist[P,1], atom_types[512,28], bond_types[1024,6], C_batch[P]
static constexpr size_t P_TOT    = (size_t)NB_B * NL * NT;     // 262144
static constexpr size_t PI_OFF   = 0;
static constexpr size_t SIG_OFF  = P_TOT * 10;
static constexpr size_t MU_OFF   = SIG_OFF + P_TOT * 10;
static constexpr size_t DIST_OFF = MU_OFF + P_TOT * 10;
static constexpr size_t AT_OFF   = DIST_OFF + P_TOT;
static constexpr size_t BD_OFF   = AT_OFF + 512 * 28;
static constexpr size_t CB_OFF   = BD_OFF + NE * 6;

typedef __attribute__((ext_vector_type(8))) short short8;
typedef __attribute__((ext_vector_type(4))) float floatx4;
typedef __attribute__((ext_vector_type(2))) float floatx2;

union U8 { short8 s8; unsigned int u[4]; };

__device__ __forceinline__ float bf2f(unsigned short u) {
    return __uint_as_float(((unsigned int)u) << 16);
}
__device__ __forceinline__ unsigned short f2bf(float f) {
    unsigned int x = __float_as_uint(f);
    x = (x + 0x7FFFu + ((x >> 16) & 1u)) >> 16;   // RNE
    return (unsigned short)x;
}
// HW packed f32x2 -> bf16x2 (v_cvt_pk_bf16_f32 on gfx950); a -> low 16.
__device__ __forceinline__ unsigned int pk2bf(float a, float b) {
    __hip_bfloat162 h = __float22bfloat162_rn(make_float2(a, b));
    return *reinterpret_cast<unsigned int*>(&h);
}
// Branchless exact ELU: max(x,0) + (exp(min(x,0)) - 1)
__device__ __forceinline__ float elu(float x) {
    return fmaxf(x, 0.f) + (__expf(fminf(x, 0.f)) - 1.f);
}

// ---------------------------------------------------------------------------
// Kernel 1: blocks [0,144) = MFMA GEMM producing zl' (16 blocks) / zt' (128
// blocks), 32 rows each; block 144 = wcomb_t; [145,201) atom_types;
// [201,225) bond_types.  (Validated R3/R4 structure; pk2bf conversions.)
// ---------------------------------------------------------------------------
__global__ __launch_bounds__(256) void k_pre(
    const float* __restrict__ hl,
    const float* __restrict__ ht,
    const int*   __restrict__ eidx,
    const float* __restrict__ W1,
    const float* __restrict__ b1,
    const float* __restrict__ gamma_,
    const float* __restrict__ beta_,
    const float* __restrict__ rmean,
    const float* __restrict__ rvar,
    const float* __restrict__ Wpi,
    const float* __restrict__ Wsig,
    const float* __restrict__ Wmu,
    const float* __restrict__ Wat,
    const float* __restrict__ bat,
    const float* __restrict__ Wbd,
    const float* __restrict__ bbd,
    unsigned short* __restrict__ zl,
    unsigned short* __restrict__ zt,
    unsigned short* __restrict__ wcomb_t,
    float* __restrict__ out_at,
    float* __restrict__ out_bd)
{
    const int blk = blockIdx.x;
    const int tid = threadIdx.x;

    if (blk < 144) {
        const bool is_l = (blk < 16);
        const int rbase = is_l ? blk * 32 : (blk - 16) * 32;
        const float* A  = is_l ? hl : ht;
        const float* Wx = W1 + (is_l ? 0 : (size_t)CF * HD);   // [128 c][128 h]
        unsigned short* Z = is_l ? zl : zt;

        const int wave = tid >> 6;
        const int lane = tid & 63;
        const int m    = lane & 15;
        const int kq   = (lane >> 4) * 8;
        const int n0   = wave * 32 + m;          // col for nt=0 (+16 for nt=1)

        floatx4 acc[2][2];
        #pragma unroll
        for (int i = 0; i < 2; ++i)
            #pragma unroll
            for (int j = 0; j < 2; ++j)
                acc[i][j] = (floatx4){0.f, 0.f, 0.f, 0.f};

        #pragma unroll
        for (int kb = 0; kb < 4; ++kb) {
            const int k0 = kb * 32 + kq;
            short8 a[2];
            #pragma unroll
            for (int mt = 0; mt < 2; ++mt) {
                const float* ap = A + (size_t)(rbase + mt * 16 + m) * CF + k0;
                const float4 f0 = *(const float4*)ap;
                const float4 f1 = *(const float4*)(ap + 4);
                U8 t;
                t.u[0] = pk2bf(f0.x, f0.y);
                t.u[1] = pk2bf(f0.z, f0.w);
                t.u[2] = pk2bf(f1.x, f1.y);
                t.u[3] = pk2bf(f1.z, f1.w);
                a[mt] = t.s8;
            }
            short8 bf[2];
            #pragma unroll
            for (int nt = 0; nt < 2; ++nt) {
                const int n = n0 + nt * 16;
                float w[8];
                #pragma unroll
                for (int j = 0; j < 8; ++j)
                    w[j] = Wx[(size_t)(k0 + j) * HD + n];
                U8 t;
                #pragma unroll
                for (int j = 0; j < 4; ++j) t.u[j] = pk2bf(w[2*j], w[2*j+1]);
                bf[nt] = t.s8;
            }
            #pragma unroll
            for (int mt = 0; mt < 2; ++mt)
                #pragma unroll
                for (int nt = 0; nt < 2; ++nt)
                    acc[mt][nt] = __builtin_amdgcn_mfma_f32_16x16x32_bf16(a[mt], bf[nt], acc[mt][nt], 0, 0, 0);
        }

        #pragma unroll
        for (int nt = 0; nt < 2; ++nt) {
            const int col = n0 + nt * 16;
            const float s   = gamma_[col] * rsqrtf(rvar[col] + 1e-4f);
            const float off = is_l ? 0.f : ((b1[col] - rmean[col]) * s + beta_[col]);
            #pragma unroll
            for (int mt = 0; mt < 2; ++mt)
                #pragma unroll
                for (int r = 0; r < 4; ++r) {
                    const int row = rbase + mt * 16 + (lane >> 4) * 4 + r;
                    Z[(size_t)row * HD + col] = f2bf(acc[mt][nt][r] * s + off);
                }
        }
    } else if (blk == 144) {
        // wcomb_t[n][k]: n 0-9 = Wpi col, 10-19 = Wsig, 20-29 = Wmu, 30-31 = 0
        for (int i = tid; i < 32 * HD; i += 256) {
            const int n = i >> 7, k = i & 127;
            float v = 0.f;
            if (n < 10)      v = Wpi [k * NK + n];
            else if (n < 20) v = Wsig[k * NK + (n - 10)];
            else if (n < 30) v = Wmu [k * NK + (n - 20)];
            wcomb_t[i] = f2bf(v);
        }
    } else if (blk < 201) {
        // atom_types: 512x28 (56 blocks * 256 = 14336)
        const int oi = (blk - 145) * 256 + tid;
        const int r = oi / 28, n = oi - r * 28;
        float acc = bat[n];
        #pragma unroll 4
        for (int c = 0; c < CF; ++c)
            acc += hl[(size_t)r * CF + c] * Wat[c * 28 + n];
        out_at[oi] = acc;
    } else {
        // bond_types: 1024x6 (24 blocks * 256 = 6144)
        const int oi = (blk - 201) * 256 + tid;
        const int e = oi / 6, n = oi - e * 6;
        const int s0 = eidx[e], s1 = eidx[NE + e];
        float acc = bbd[n];
        #pragma unroll 4
        for (int c = 0; c < CF; ++c) {
            acc += hl[(size_t)s0 * CF + c] * Wbd[c * 6 + n];
            acc += hl[(size_t)s1 * CF + c] * Wbd[(CF + c) * 6 + n];
        }
        out_bd[oi] = acc;
    }
}

// ---------------------------------------------------------------------------
// Kernel 2: one block per (b, l, chunk-of-128-t): 2048 blocks, 256 threads.
// A-fragments = ELU(zl'+zt') computed directly from global (L2-resident),
// branchless ELU + HW pk2bf pack; heads via MFMA; Dl stride 34 (conflict-free);
// fp32 epilogues. 2 barriers total.
// ---------------------------------------------------------------------------
__global__ __launch_bounds__(256) void k_main(
    const unsigned short* __restrict__ zl,
    const unsigned short* __restrict__ zt,
    const unsigned short* __restrict__ wcomb_t,
    const float* __restrict__ bpi,
    const float* __restrict__ bsig,
    const float* __restrict__ bmu,
    const float* __restrict__ hlpos,
    const float* __restrict__ htpos,
    float* __restrict__ out)
{
    __shared__ float Dl[128 * 34];   // 17408 B, stride 34 => <=2-way banks
    __shared__ float biass[32];
    __shared__ float pls[3];

    const int tid  = threadIdx.x;
    const int blk  = blockIdx.x;
    const int b    = blk >> 8;
    const int l    = (blk >> 2) & 63;
    const int ch   = blk & 3;
    const int lane = tid & 63;
    const int wave = tid >> 6;
    const int m    = lane & 15;
    const int quad = lane >> 4;

    if (tid < 32) {
        float v = 0.f;
        if (tid < 10)      v = bpi[tid];
        else if (tid < 20) v = bsig[tid - 10];
        else if (tid < 30) v = bmu[tid - 20];
        biass[tid] = v;
    } else if (tid < 35) {
        pls[tid - 32] = hlpos[(size_t)(b * NL + l) * 3 + (tid - 32)];
    }

    // B fragments: single 16B loads from transposed head weights
    short8 bfrag[2][4];
    #pragma unroll
    for (int nt = 0; nt < 2; ++nt)
        #pragma unroll
        for (int kb = 0; kb < 4; ++kb)
            bfrag[nt][kb] = *(const short8*)(wcomb_t + (size_t)(nt * 16 + m) * HD + kb * 32 + quad * 8);

    // ---- stage A: direct A-frag compute + MFMA ----
    const unsigned short* zlr = zl + (size_t)(b * NL + l) * HD;
    const unsigned short* ztb = zt + (size_t)(b * NT + ch * 128) * HD;

    floatx4 acc[2][2];
    #pragma unroll
    for (int i = 0; i < 2; ++i)
        #pragma unroll
        for (int j = 0; j < 2; ++j)
            acc[i][j] = (floatx4){0.f, 0.f, 0.f, 0.f};

    #pragma unroll
    for (int kb = 0; kb < 4; ++kb) {
        const int k0 = kb * 32 + quad * 8;
        const short8 zlv = *(const short8*)(zlr + k0);
        float zf[8];
        #pragma unroll
        for (int j = 0; j < 8; ++j) zf[j] = bf2f((unsigned short)zlv[j]);

        short8 a[2];
        #pragma unroll
        for (int mt = 0; mt < 2; ++mt) {
            const int row = wave * 32 + mt * 16 + m;
            const short8 ztv = *(const short8*)(ztb + (size_t)row * HD + k0);
            float e[8];
            #pragma unroll
            for (int j = 0; j < 8; ++j)
                e[j] = elu(zf[j] + bf2f((unsigned short)ztv[j]));
            U8 t;
            #pragma unroll
            for (int j = 0; j < 4; ++j) t.u[j] = pk2bf(e[2*j], e[2*j+1]);
            a[mt] = t.s8;
        }
        #pragma unroll
        for (int mt = 0; mt < 2; ++mt)
            #pragma unroll
            for (int nt = 0; nt < 2; ++nt)
                acc[mt][nt] = __builtin_amdgcn_mfma_f32_16x16x32_bf16(a[mt], bfrag[nt][kb], acc[mt][nt], 0, 0, 0);
    }

    // D: col = lane&15, row = quad*4 + r   [validated R3/R4]
    #pragma unroll
    for (int mt = 0; mt < 2; ++mt)
        #pragma unroll
        for (int nt = 0; nt < 2; ++nt)
            #pragma unroll
            for (int r = 0; r < 4; ++r) {
                const int row = wave * 32 + mt * 16 + quad * 4 + r;
                const int col = nt * 16 + m;
                Dl[row * 34 + col] = acc[mt][nt][r];
            }
    __syncthreads();

    // ---- stage B: epilogues (fp32 stores) ----
    const size_t gp = ((size_t)(b * NL + l)) * NT + ch * 128 + (tid & 127);
    if (tid < 128) {
        const int p = tid;
        float v[10];
        float mx = -1e30f;
        #pragma unroll
        for (int n = 0; n < 10; ++n) {
            v[n] = Dl[p * 34 + n] + biass[n];
            mx = fmaxf(mx, v[n]);
        }
        float s = 0.f;
        #pragma unroll
        for (int n = 0; n < 10; ++n) { v[n] = __expf(v[n] - mx); s += v[n]; }
        const float inv = 1.f / s;
        floatx2* po = (floatx2*)(out + PI_OFF + gp * 10);
        #pragma unroll
        for (int n = 0; n < 5; ++n) po[n] = (floatx2){v[2*n] * inv, v[2*n+1] * inv};
    } else {
        const int p = tid - 128;
        float sg[10], mv[10];
        #pragma unroll
        for (int n = 0; n < 10; ++n) {
            sg[n] = elu(Dl[p * 34 + 10 + n] + biass[10 + n]) + 1.1f;
            mv[n] = elu(Dl[p * 34 + 20 + n] + biass[20 + n]) + 1.0f;
        }
        floatx2* ps = (floatx2*)(out + SIG_OFF + gp * 10);
        floatx2* pm = (floatx2*)(out + MU_OFF  + gp * 10);
        #pragma unroll
        for (int n = 0; n < 5; ++n) {
            ps[n] = (floatx2){sg[2*n], sg[2*n+1]};
            pm[n] = (floatx2){mv[2*n], mv[2*n+1]};
        }
        const int t = ch * 128 + p;
        const size_t pb = (size_t)(b * NT + t) * 3;
        const float dx = pls[0] - htpos[pb + 0];
        const float dy = pls[1] - htpos[pb + 1];
        const float dz = pls[2] - htpos[pb + 2];
        out[DIST_OFF + gp] = sqrtf(dx * dx + dy * dy + dz * dz);
        out[CB_OFF + gp]   = (float)b;
    }
}

// ---------------------------------------------------------------------------
extern "C" void kernel_launch(void* const* d_in, const int* in_sizes, int n_in,
                              void* d_out, int out_size, void* d_ws, size_t ws_size,
                              hipStream_t stream)
{
    const float* hl     = (const float*)d_in[0];
    const float* ht     = (const float*)d_in[1];
    const float* hlpos  = (const float*)d_in[2];
    const float* htpos  = (const float*)d_in[3];
    const int*   eidx   = (const int*)d_in[4];
    const float* W1     = (const float*)d_in[5];
    const float* b1     = (const float*)d_in[6];
    const float* gamma_ = (const float*)d_in[7];
    const float* beta_  = (const float*)d_in[8];
    const float* rmean  = (const float*)d_in[9];
    const float* rvar   = (const float*)d_in[10];
    const float* Wpi    = (const float*)d_in[11];
    const float* bpi    = (const float*)d_in[12];
    const float* Wsig   = (const float*)d_in[13];
    const float* bsig   = (const float*)d_in[14];
    const float* Wmu    = (const float*)d_in[15];
    const float* bmu    = (const float*)d_in[16];
    const float* Wat    = (const float*)d_in[17];
    const float* bat    = (const float*)d_in[18];
    const float* Wbd    = (const float*)d_in[19];
    const float* bbd    = (const float*)d_in[20];

    float* out = (float*)d_out;
    unsigned short* ws  = (unsigned short*)d_ws;
    unsigned short* zl      = ws;                          // 512*128 bf16
    unsigned short* zt      = ws + 512 * 128;              // 4096*128 bf16
    unsigned short* wcomb_t = ws + 512 * 128 + 4096 * 128; // 32*128 bf16

    k_pre<<<225, 256, 0, stream>>>(hl, ht, eidx, W1, b1, gamma_, beta_, rmean, rvar,
                                   Wpi, Wsig, Wmu, Wat, bat, Wbd, bbd,
                                   zl, zt, wcomb_t, out + AT_OFF, out + BD_OFF);
    k_main<<<2048, 256, 0, stream>>>(zl, zt, wcomb_t, bpi, bsig, bmu, hlpos, htpos, out);
}

// Round 7
// 132.302 us; speedup vs baseline: 1.1700x; 1.0609x over previous
//
#include <hip/hip_runtime.h>
#include <hip/hip_bf16.h>
#include <cstdint>
#include <cstddef>

// Problem constants
#define NB_B 8
#define NL   64
#define NT   512
#define CF   128
#define HD   128
#define NK   10
#define NE   1024

// d_out flat offsets (fp32 elements), reference return order:
// pi[P,10], sigma[P,10], mu[P,10], dist[P,1], atom_types[512,28], bond_types[1024,6], C_batch[P]
static constexpr size_t P_TOT    = (size_t)NB_B * NL * NT;     // 262144
static constexpr size_t PI_OFF   = 0;
static constexpr size_t SIG_OFF  = P_TOT * 10;
static constexpr size_t MU_OFF   = SIG_OFF + P_TOT * 10;
static constexpr size_t DIST_OFF = MU_OFF + P_TOT * 10;
static constexpr size_t AT_OFF   = DIST_OFF + P_TOT;
static constexpr size_t BD_OFF   = AT_OFF + 512 * 28;
static constexpr size_t CB_OFF   = BD_OFF + NE * 6;

typedef __attribute__((ext_vector_type(8))) short short8;
typedef __attribute__((ext_vector_type(4))) float floatx4;
typedef __attribute__((ext_vector_type(2))) float floatx2;

union U8 { short8 s8; unsigned int u[4]; };

__device__ __forceinline__ float bf2f(unsigned short u) {
    return __uint_as_float(((unsigned int)u) << 16);
}
__device__ __forceinline__ unsigned short f2bf(float f) {
    unsigned int x = __float_as_uint(f);
    x = (x + 0x7FFFu + ((x >> 16) & 1u)) >> 16;   // RNE
    return (unsigned short)x;
}
// HW packed f32x2 -> bf16x2 (v_cvt_pk_bf16_f32 on gfx950); a -> low 16.
__device__ __forceinline__ unsigned int pk2bf(float a, float b) {
    __hip_bfloat162 h = __float22bfloat162_rn(make_float2(a, b));
    return *reinterpret_cast<unsigned int*>(&h);
}
// Branchless exact ELU: max(x,0) + (exp(min(x,0)) - 1)
__device__ __forceinline__ float elu(float x) {
    return fmaxf(x, 0.f) + (__expf(fminf(x, 0.f)) - 1.f);
}

// ---------------------------------------------------------------------------
// Kernel 1 (slim): blocks [0,144) = MFMA GEMM producing zl' (16) / zt' (128),
// 32 rows each; block 144 = wcomb_t. atom/bond moved to k_main's dispatch.
// ---------------------------------------------------------------------------
__global__ __launch_bounds__(256) void k_pre(
    const float* __restrict__ hl,
    const float* __restrict__ ht,
    const float* __restrict__ W1,
    const float* __restrict__ b1,
    const float* __restrict__ gamma_,
    const float* __restrict__ beta_,
    const float* __restrict__ rmean,
    const float* __restrict__ rvar,
    const float* __restrict__ Wpi,
    const float* __restrict__ Wsig,
    const float* __restrict__ Wmu,
    unsigned short* __restrict__ zl,
    unsigned short* __restrict__ zt,
    unsigned short* __restrict__ wcomb_t)
{
    const int blk = blockIdx.x;
    const int tid = threadIdx.x;

    if (blk < 144) {
        const bool is_l = (blk < 16);
        const int rbase = is_l ? blk * 32 : (blk - 16) * 32;
        const float* A  = is_l ? hl : ht;
        const float* Wx = W1 + (is_l ? 0 : (size_t)CF * HD);   // [128 c][128 h]
        unsigned short* Z = is_l ? zl : zt;

        const int wave = tid >> 6;
        const int lane = tid & 63;
        const int m    = lane & 15;
        const int kq   = (lane >> 4) * 8;
        const int n0   = wave * 32 + m;          // col for nt=0 (+16 for nt=1)

        floatx4 acc[2][2];
        #pragma unroll
        for (int i = 0; i < 2; ++i)
            #pragma unroll
            for (int j = 0; j < 2; ++j)
                acc[i][j] = (floatx4){0.f, 0.f, 0.f, 0.f};

        #pragma unroll
        for (int kb = 0; kb < 4; ++kb) {
            const int k0 = kb * 32 + kq;
            short8 a[2];
            #pragma unroll
            for (int mt = 0; mt < 2; ++mt) {
                const float* ap = A + (size_t)(rbase + mt * 16 + m) * CF + k0;
                const float4 f0 = *(const float4*)ap;
                const float4 f1 = *(const float4*)(ap + 4);
                U8 t;
                t.u[0] = pk2bf(f0.x, f0.y);
                t.u[1] = pk2bf(f0.z, f0.w);
                t.u[2] = pk2bf(f1.x, f1.y);
                t.u[3] = pk2bf(f1.z, f1.w);
                a[mt] = t.s8;
            }
            short8 bf[2];
            #pragma unroll
            for (int nt = 0; nt < 2; ++nt) {
                const int n = n0 + nt * 16;
                float w[8];
                #pragma unroll
                for (int j = 0; j < 8; ++j)
                    w[j] = Wx[(size_t)(k0 + j) * HD + n];
                U8 t;
                #pragma unroll
                for (int j = 0; j < 4; ++j) t.u[j] = pk2bf(w[2*j], w[2*j+1]);
                bf[nt] = t.s8;
            }
            #pragma unroll
            for (int mt = 0; mt < 2; ++mt)
                #pragma unroll
                for (int nt = 0; nt < 2; ++nt)
                    acc[mt][nt] = __builtin_amdgcn_mfma_f32_16x16x32_bf16(a[mt], bf[nt], acc[mt][nt], 0, 0, 0);
        }

        #pragma unroll
        for (int nt = 0; nt < 2; ++nt) {
            const int col = n0 + nt * 16;
            const float s   = gamma_[col] * rsqrtf(rvar[col] + 1e-4f);
            const float off = is_l ? 0.f : ((b1[col] - rmean[col]) * s + beta_[col]);
            #pragma unroll
            for (int mt = 0; mt < 2; ++mt)
                #pragma unroll
                for (int r = 0; r < 4; ++r) {
                    const int row = rbase + mt * 16 + (lane >> 4) * 4 + r;
                    Z[(size_t)row * HD + col] = f2bf(acc[mt][nt][r] * s + off);
                }
        }
    } else {
        // wcomb_t[n][k]: n 0-9 = Wpi col, 10-19 = Wsig, 20-29 = Wmu, 30-31 = 0
        for (int i = tid; i < 32 * HD; i += 256) {
            const int n = i >> 7, k = i & 127;
            float v = 0.f;
            if (n < 10)      v = Wpi [k * NK + n];
            else if (n < 20) v = Wsig[k * NK + (n - 10)];
            else if (n < 30) v = Wmu [k * NK + (n - 20)];
            wcomb_t[i] = f2bf(v);
        }
    }
}

// ---------------------------------------------------------------------------
// Kernel 2: blocks [0,2048) = one per (b, l, chunk-of-128-t) — R6-validated
// main path. Blocks [2048,2052) = atom_types MFMA ([512,128]@[128,28]).
// Blocks [2052,2060) = bond_types MFMA (gathered [1024,256]@[256,6]).
// atom/bond read only d_in + d_out (no ws) => safe in this dispatch.
// ---------------------------------------------------------------------------
__global__ __launch_bounds__(256) void k_main(
    const unsigned short* __restrict__ zl,
    const unsigned short* __restrict__ zt,
    const unsigned short* __restrict__ wcomb_t,
    const float* __restrict__ bpi,
    const float* __restrict__ bsig,
    const float* __restrict__ bmu,
    const float* __restrict__ hlpos,
    const float* __restrict__ htpos,
    const float* __restrict__ hl,
    const int*   __restrict__ eidx,
    const float* __restrict__ Wat,
    const float* __restrict__ bat,
    const float* __restrict__ Wbd,
    const float* __restrict__ bbd,
    float* __restrict__ out)
{
    __shared__ float Dl[128 * 34];   // 17408 B, stride 34 => <=2-way banks
    __shared__ float biass[32];
    __shared__ float pls[3];

    const int tid  = threadIdx.x;
    const int blk  = blockIdx.x;
    const int lane = tid & 63;
    const int wave = tid >> 6;
    const int m    = lane & 15;
    const int quad = lane >> 4;

    if (blk >= 2048) {
        const int ab = blk - 2048;
        if (ab < 4) {
            // ---- atom_types: rows ab*128 + wave*32 .. +31 ----
            const int rbase = ab * 128 + wave * 32;
            floatx4 acc[2][2];
            #pragma unroll
            for (int i = 0; i < 2; ++i)
                #pragma unroll
                for (int j = 0; j < 2; ++j)
                    acc[i][j] = (floatx4){0.f, 0.f, 0.f, 0.f};
            #pragma unroll
            for (int kb = 0; kb < 4; ++kb) {
                const int k0 = kb * 32 + quad * 8;
                short8 a[2];
                #pragma unroll
                for (int mt = 0; mt < 2; ++mt) {
                    const float* ap = hl + (size_t)(rbase + mt * 16 + m) * CF + k0;
                    const float4 f0 = *(const float4*)ap;
                    const float4 f1 = *(const float4*)(ap + 4);
                    U8 t;
                    t.u[0] = pk2bf(f0.x, f0.y);
                    t.u[1] = pk2bf(f0.z, f0.w);
                    t.u[2] = pk2bf(f1.x, f1.y);
                    t.u[3] = pk2bf(f1.z, f1.w);
                    a[mt] = t.s8;
                }
                short8 bf[2];
                #pragma unroll
                for (int nt = 0; nt < 2; ++nt) {
                    const int n = nt * 16 + m;
                    const int nc = (n < 28) ? n : 0;
                    #pragma unroll
                    for (int j = 0; j < 8; ++j) {
                        const float w = Wat[(size_t)(k0 + j) * 28 + nc];
                        bf[nt][j] = (short)f2bf((n < 28) ? w : 0.f);
                    }
                }
                #pragma unroll
                for (int mt = 0; mt < 2; ++mt)
                    #pragma unroll
                    for (int nt = 0; nt < 2; ++nt)
                        acc[mt][nt] = __builtin_amdgcn_mfma_f32_16x16x32_bf16(a[mt], bf[nt], acc[mt][nt], 0, 0, 0);
            }
            #pragma unroll
            for (int nt = 0; nt < 2; ++nt) {
                const int col = nt * 16 + m;
                if (col < 28) {
                    const float bias = bat[col];
                    #pragma unroll
                    for (int mt = 0; mt < 2; ++mt)
                        #pragma unroll
                        for (int r = 0; r < 4; ++r) {
                            const int row = rbase + mt * 16 + quad * 4 + r;
                            out[AT_OFF + (size_t)row * 28 + col] = acc[mt][nt][r] + bias;
                        }
                }
            }
        } else {
            // ---- bond_types: rows (ab-4)*128 + wave*32 .. +31, K=256 ----
            const int rbase = (ab - 4) * 128 + wave * 32;
            const int e0 = rbase + m, e1 = rbase + 16 + m;
            const int s00 = eidx[e0], s01 = eidx[NE + e0];
            const int s10 = eidx[e1], s11 = eidx[NE + e1];
            floatx4 acc[2];
            acc[0] = (floatx4){0.f, 0.f, 0.f, 0.f};
            acc[1] = (floatx4){0.f, 0.f, 0.f, 0.f};
            const int nc = (m < 6) ? m : 0;
            #pragma unroll
            for (int kb = 0; kb < 8; ++kb) {
                const int k0 = kb * 32 + quad * 8;
                const bool lo = (k0 < 128);
                const int off = lo ? k0 : (k0 - 128);
                short8 a[2];
                #pragma unroll
                for (int mt = 0; mt < 2; ++mt) {
                    const int src = lo ? (mt ? s10 : s00) : (mt ? s11 : s01);
                    const float* ap = hl + (size_t)src * CF + off;
                    const float4 f0 = *(const float4*)ap;
                    const float4 f1 = *(const float4*)(ap + 4);
                    U8 t;
                    t.u[0] = pk2bf(f0.x, f0.y);
                    t.u[1] = pk2bf(f0.z, f0.w);
                    t.u[2] = pk2bf(f1.x, f1.y);
                    t.u[3] = pk2bf(f1.z, f1.w);
                    a[mt] = t.s8;
                }
                short8 bf;
                #pragma unroll
                for (int j = 0; j < 8; ++j) {
                    const float w = Wbd[(size_t)(k0 + j) * 6 + nc];
                    bf[j] = (short)f2bf((m < 6) ? w : 0.f);
                }
                acc[0] = __builtin_amdgcn_mfma_f32_16x16x32_bf16(a[0], bf, acc[0], 0, 0, 0);
                acc[1] = __builtin_amdgcn_mfma_f32_16x16x32_bf16(a[1], bf, acc[1], 0, 0, 0);
            }
            if (m < 6) {
                const float bias = bbd[m];
                #pragma unroll
                for (int mt = 0; mt < 2; ++mt)
                    #pragma unroll
                    for (int r = 0; r < 4; ++r) {
                        const int row = rbase + mt * 16 + quad * 4 + r;
                        out[BD_OFF + (size_t)row * 6 + m] = acc[mt][r] + bias;
                    }
            }
        }
        return;
    }

    const int b  = blk >> 8;
    const int l  = (blk >> 2) & 63;
    const int ch = blk & 3;

    if (tid < 32) {
        float v = 0.f;
        if (tid < 10)      v = bpi[tid];
        else if (tid < 20) v = bsig[tid - 10];
        else if (tid < 30) v = bmu[tid - 20];
        biass[tid] = v;
    } else if (tid < 35) {
        pls[tid - 32] = hlpos[(size_t)(b * NL + l) * 3 + (tid - 32)];
    }

    // B fragments: single 16B loads from transposed head weights
    short8 bfrag[2][4];
    #pragma unroll
    for (int nt = 0; nt < 2; ++nt)
        #pragma unroll
        for (int kb = 0; kb < 4; ++kb)
            bfrag[nt][kb] = *(const short8*)(wcomb_t + (size_t)(nt * 16 + m) * HD + kb * 32 + quad * 8);

    // ---- stage A: direct A-frag compute + MFMA ----
    const unsigned short* zlr = zl + (size_t)(b * NL + l) * HD;
    const unsigned short* ztb = zt + (size_t)(b * NT + ch * 128) * HD;

    floatx4 acc[2][2];
    #pragma unroll
    for (int i = 0; i < 2; ++i)
        #pragma unroll
        for (int j = 0; j < 2; ++j)
            acc[i][j] = (floatx4){0.f, 0.f, 0.f, 0.f};

    #pragma unroll
    for (int kb = 0; kb < 4; ++kb) {
        const int k0 = kb * 32 + quad * 8;
        const short8 zlv = *(const short8*)(zlr + k0);
        float zf[8];
        #pragma unroll
        for (int j = 0; j < 8; ++j) zf[j] = bf2f((unsigned short)zlv[j]);

        short8 a[2];
        #pragma unroll
        for (int mt = 0; mt < 2; ++mt) {
            const int row = wave * 32 + mt * 16 + m;
            const short8 ztv = *(const short8*)(ztb + (size_t)row * HD + k0);
            float e[8];
            #pragma unroll
            for (int j = 0; j < 8; ++j)
                e[j] = elu(zf[j] + bf2f((unsigned short)ztv[j]));
            U8 t;
            #pragma unroll
            for (int j = 0; j < 4; ++j) t.u[j] = pk2bf(e[2*j], e[2*j+1]);
            a[mt] = t.s8;
        }
        #pragma unroll
        for (int mt = 0; mt < 2; ++mt)
            #pragma unroll
            for (int nt = 0; nt < 2; ++nt)
                acc[mt][nt] = __builtin_amdgcn_mfma_f32_16x16x32_bf16(a[mt], bfrag[nt][kb], acc[mt][nt], 0, 0, 0);
    }

    // D: col = lane&15, row = quad*4 + r   [validated R3/R4]
    #pragma unroll
    for (int mt = 0; mt < 2; ++mt)
        #pragma unroll
        for (int nt = 0; nt < 2; ++nt)
            #pragma unroll
            for (int r = 0; r < 4; ++r) {
                const int row = wave * 32 + mt * 16 + quad * 4 + r;
                const int col = nt * 16 + m;
                Dl[row * 34 + col] = acc[mt][nt][r];
            }
    __syncthreads();

    // ---- stage B: epilogues (fp32 stores) ----
    const size_t gp = ((size_t)(b * NL + l)) * NT + ch * 128 + (tid & 127);
    if (tid < 128) {
        const int p = tid;
        float v[10];
        float mx = -1e30f;
        #pragma unroll
        for (int n = 0; n < 10; ++n) {
            v[n] = Dl[p * 34 + n] + biass[n];
            mx = fmaxf(mx, v[n]);
        }
        float s = 0.f;
        #pragma unroll
        for (int n = 0; n < 10; ++n) { v[n] = __expf(v[n] - mx); s += v[n]; }
        const float inv = 1.f / s;
        floatx2* po = (floatx2*)(out + PI_OFF + gp * 10);
        #pragma unroll
        for (int n = 0; n < 5; ++n) po[n] = (floatx2){v[2*n] * inv, v[2*n+1] * inv};
    } else {
        const int p = tid - 128;
        float sg[10], mv[10];
        #pragma unroll
        for (int n = 0; n < 10; ++n) {
            sg[n] = elu(Dl[p * 34 + 10 + n] + biass[10 + n]) + 1.1f;
            mv[n] = elu(Dl[p * 34 + 20 + n] + biass[20 + n]) + 1.0f;
        }
        floatx2* ps = (floatx2*)(out + SIG_OFF + gp * 10);
        floatx2* pm = (floatx2*)(out + MU_OFF  + gp * 10);
        #pragma unroll
        for (int n = 0; n < 5; ++n) {
            ps[n] = (floatx2){sg[2*n], sg[2*n+1]};
            pm[n] = (floatx2){mv[2*n], mv[2*n+1]};
        }
        const int t = ch * 128 + p;
        const size_t pb = (size_t)(b * NT + t) * 3;
        const float dx = pls[0] - htpos[pb + 0];
        const float dy = pls[1] - htpos[pb + 1];
        const float dz = pls[2] - htpos[pb + 2];
        out[DIST_OFF + gp] = sqrtf(dx * dx + dy * dy + dz * dz);
        out[CB_OFF + gp]   = (float)b;
    }
}

// ---------------------------------------------------------------------------
extern "C" void kernel_launch(void* const* d_in, const int* in_sizes, int n_in,
                              void* d_out, int out_size, void* d_ws, size_t ws_size,
                              hipStream_t stream)
{
    const float* hl     = (const float*)d_in[0];
    const float* ht     = (const float*)d_in[1];
    const float* hlpos  = (const float*)d_in[2];
    const float* htpos  = (const float*)d_in[3];
    const int*   eidx   = (const int*)d_in[4];
    const float* W1     = (const float*)d_in[5];
    const float* b1     = (const float*)d_in[6];
    const float* gamma_ = (const float*)d_in[7];
    const float* beta_  = (const float*)d_in[8];
    const float* rmean  = (const float*)d_in[9];
    const float* rvar   = (const float*)d_in[10];
    const float* Wpi    = (const float*)d_in[11];
    const float* bpi    = (const float*)d_in[12];
    const float* Wsig   = (const float*)d_in[13];
    const float* bsig   = (const float*)d_in[14];
    const float* Wmu    = (const float*)d_in[15];
    const float* bmu    = (const float*)d_in[16];
    const float* Wat    = (const float*)d_in[17];
    const float* bat    = (const float*)d_in[18];
    const float* Wbd    = (const float*)d_in[19];
    const float* bbd    = (const float*)d_in[20];

    float* out = (float*)d_out;
    unsigned short* ws  = (unsigned short*)d_ws;
    unsigned short* zl      = ws;                          // 512*128 bf16
    unsigned short* zt      = ws + 512 * 128;              // 4096*128 bf16
    unsigned short* wcomb_t = ws + 512 * 128 + 4096 * 128; // 32*128 bf16

    k_pre<<<145, 256, 0, stream>>>(hl, ht, W1, b1, gamma_, beta_, rmean, rvar,
                                   Wpi, Wsig, Wmu, zl, zt, wcomb_t);
    k_main<<<2060, 256, 0, stream>>>(zl, zt, wcomb_t, bpi, bsig, bmu, hlpos, htpos,
                                     hl, eidx, Wat, bat, Wbd, bbd, out);
}